// Round 1
// baseline (123.188 us; speedup 1.0000x reference)
//
#include <hip/hip_runtime.h>

// Problem constants
#define Bq 32
#define Sq 2048
#define Dq 128
#define Tq 8
#define Mq (Bq * Sq)   // 65536 rows

typedef __attribute__((ext_vector_type(8))) short bf16x8;
typedef __attribute__((ext_vector_type(4))) float f32x4;

static __device__ __forceinline__ unsigned short f2bf(float f) {
    // round-to-nearest-even fp32 -> bf16 (inputs are finite gaussians; no NaN handling needed)
    unsigned int u = __float_as_uint(f);
    unsigned int r = (u + 0x7FFFu + ((u >> 16) & 1u)) >> 16;
    return (unsigned short)r;
}

// ---------------------------------------------------------------------------
// Kernel 1: W [T,D,D] fp32 -> bf16, swizzled into MFMA B-fragment order.
// For mfma_f32_16x16x32_bf16, B operand: lane holds B[k = quad*8 + j][n = lane&15]
// = W[e = n][d = k]. Fragment element (t, ntile, kstep, lane, j) reads
// W[t][ntile*16 + (lane&15)][kstep*32 + (lane>>4)*8 + j].
// Output flat index = (((t*8 + n)*4 + k)*64 + lane)*8 + j  -> hot-loop loads
// become lane-contiguous 16B = perfectly coalesced 1KB/wave instructions.
// ---------------------------------------------------------------------------
__global__ void prep_kernel(const float* __restrict__ W, unsigned short* __restrict__ wsw) {
    int i = blockIdx.x * 256 + threadIdx.x;   // grid covers exactly T*D*D = 131072
    int j    = i & 7;
    int lane = (i >> 3) & 63;
    int k    = (i >> 9) & 3;
    int n    = (i >> 11) & 7;
    int t    = i >> 14;
    int e = n * 16 + (lane & 15);
    int d = k * 32 + (lane >> 4) * 8 + j;
    wsw[i] = f2bf(W[(t * 128 + e) * 128 + d]);
}

// ---------------------------------------------------------------------------
// Kernel 2: sim[m, t] = softmax_t( dot(x_m, p_t) / (|x_m| |p_t|) ), fp32.
// One thread per row; p staged in LDS (broadcast reads).
// ---------------------------------------------------------------------------
__global__ __launch_bounds__(256) void sim_kernel(const float* __restrict__ x,
                                                  const float* __restrict__ p,
                                                  float* __restrict__ sim) {
    __shared__ float4 p4[Tq][32];
    __shared__ float  pinv[Tq];
    int tid = threadIdx.x;
    // stage p: 8*128 floats = 256 float4
    reinterpret_cast<float4*>(&p4[0][0])[tid] = reinterpret_cast<const float4*>(p)[tid];
    __syncthreads();
    if (tid < Tq) {
        float s = 0.f;
        #pragma unroll
        for (int i = 0; i < 32; i++) {
            float4 v = p4[tid][i];
            s += v.x * v.x + v.y * v.y + v.z * v.z + v.w * v.w;
        }
        pinv[tid] = rsqrtf(s);
    }
    __syncthreads();

    int m = blockIdx.x * 256 + tid;
    const float4* xr = reinterpret_cast<const float4*>(x) + (size_t)m * 32;
    float acc[Tq];
    #pragma unroll
    for (int t = 0; t < Tq; t++) acc[t] = 0.f;
    float nrm = 0.f;
    #pragma unroll 4
    for (int i = 0; i < 32; i++) {
        float4 v = xr[i];
        nrm += v.x * v.x + v.y * v.y + v.z * v.z + v.w * v.w;
        #pragma unroll
        for (int t = 0; t < Tq; t++) {
            float4 pv = p4[t][i];
            acc[t] += v.x * pv.x + v.y * pv.y + v.z * pv.z + v.w * pv.w;
        }
    }
    float xinv = rsqrtf(nrm);
    float c[Tq], mx = -1e30f;
    #pragma unroll
    for (int t = 0; t < Tq; t++) {
        c[t] = acc[t] * xinv * pinv[t];
        mx = fmaxf(mx, c[t]);
    }
    float sum = 0.f;
    #pragma unroll
    for (int t = 0; t < Tq; t++) { c[t] = __expf(c[t] - mx); sum += c[t]; }
    float inv = 1.f / sum;
    float* so = sim + (size_t)m * Tq;
    #pragma unroll
    for (int t = 0; t < Tq; t++) so[t] = c[t] * inv;
}

// ---------------------------------------------------------------------------
// Kernel 3: out[m,e] = x[m,e] + sum_t sim[m,t] * (sum_d x[m,d] W[t,e,d] + bx[t,e])
// Block = 256 thr (4 waves), tile = 128 rows x 128 cols (full E).
// Wave (wid>>1, wid&1) owns a 64x64 quadrant = 4x4 tiles of 16x16.
// A-fragments (X) loaded to registers ONCE, reused across all 8 transforms.
// B-fragments loaded straight from L2 (pre-swizzled, coalesced).
// ---------------------------------------------------------------------------
__global__ __launch_bounds__(256, 2) void main_kernel(const float* __restrict__ x,
                                                      const unsigned short* __restrict__ wsw,
                                                      const float* __restrict__ bx,
                                                      const float* __restrict__ simg,
                                                      float* __restrict__ out) {
    __shared__ unsigned short xs[128][136];  // +8 ushort pad (16B) keeps b128 alignment
    __shared__ float simT[Tq][128];          // sim transposed -> b128 per (t, mtile)
    __shared__ float bxl[Tq][128];
    int tid = threadIdx.x;
    size_t m0 = (size_t)blockIdx.x * 128;

    // --- stage X tile -> bf16 LDS (coalesced float4 reads) ---
    const float4* xg4 = reinterpret_cast<const float4*>(x + m0 * 128);
    #pragma unroll
    for (int it = 0; it < 16; it++) {
        int flat = it * 256 + tid;       // 4096 float4 per tile
        int row = flat >> 5;             // 32 float4 per row
        int c4  = flat & 31;
        float4 v = xg4[flat];
        ushort4 b;
        b.x = f2bf(v.x); b.y = f2bf(v.y); b.z = f2bf(v.z); b.w = f2bf(v.w);
        *reinterpret_cast<ushort4*>(&xs[row][c4 * 4]) = b;
    }
    // --- stage sim (transpose [m][t] -> [t][m]) ---
    {
        float4 sv = reinterpret_cast<const float4*>(simg + m0 * Tq)[tid];  // 1024 floats
        int mloc = tid >> 1;
        int t0   = (tid & 1) * 4;
        simT[t0 + 0][mloc] = sv.x;
        simT[t0 + 1][mloc] = sv.y;
        simT[t0 + 2][mloc] = sv.z;
        simT[t0 + 3][mloc] = sv.w;
    }
    // --- stage bias ---
    reinterpret_cast<float4*>(&bxl[0][0])[tid] = reinterpret_cast<const float4*>(bx)[tid];
    __syncthreads();

    int wid  = tid >> 6;
    int lane = tid & 63;
    int l16  = lane & 15;
    int quad = lane >> 4;
    int mrow = (wid >> 1) * 64;   // 0 / 64
    int ncol = (wid & 1) * 64;    // 0 / 64

    // A fragments: lane holds A[m=lane&15][k=quad*8+j]; held for the whole kernel.
    bf16x8 a[4][4];
    #pragma unroll
    for (int mt = 0; mt < 4; mt++)
        #pragma unroll
        for (int k = 0; k < 4; k++)
            a[mt][k] = *reinterpret_cast<const bf16x8*>(&xs[mrow + mt * 16 + l16][k * 32 + quad * 8]);

    f32x4 o[4][4] = {};  // persistent weighted output accumulators

    #pragma unroll 1
    for (int t = 0; t < Tq; t++) {
        // per-row sim weights for this transform: rows mt*16 + quad*4 + r
        f32x4 s[4];
        #pragma unroll
        for (int mt = 0; mt < 4; mt++)
            s[mt] = *reinterpret_cast<const f32x4*>(&simT[t][mrow + mt * 16 + quad * 4]);

        #pragma unroll
        for (int n = 0; n < 4; n++) {
            int nt = (ncol >> 4) + n;   // global n-tile 0..7
            const bf16x8* bp = reinterpret_cast<const bf16x8*>(wsw) + ((size_t)(t * 8 + nt) * 4) * 64 + lane;
            f32x4 y[4] = {};
            #pragma unroll
            for (int k = 0; k < 4; k++) {
                bf16x8 bfrag = bp[(size_t)k * 64];
                #pragma unroll
                for (int mt = 0; mt < 4; mt++)
                    y[mt] = __builtin_amdgcn_mfma_f32_16x16x32_bf16(a[mt][k], bfrag, y[mt], 0, 0, 0);
            }
            float bias = bxl[t][ncol + n * 16 + l16];
            #pragma unroll
            for (int mt = 0; mt < 4; mt++)
                #pragma unroll
                for (int r = 0; r < 4; r++)
                    o[mt][n][r] += s[mt][r] * (y[mt][r] + bias);
        }
    }

    // --- epilogue: fp32 residual + store. C/D layout: col=lane&15, row=quad*4+reg ---
    #pragma unroll
    for (int mt = 0; mt < 4; mt++)
        #pragma unroll
        for (int r = 0; r < 4; r++) {
            size_t row = m0 + mrow + mt * 16 + quad * 4 + r;
            #pragma unroll
            for (int n = 0; n < 4; n++) {
                size_t idx = row * 128 + ncol + n * 16 + l16;
                out[idx] = x[idx] + o[mt][n][r];
            }
        }
}

extern "C" void kernel_launch(void* const* d_in, const int* in_sizes, int n_in,
                              void* d_out, int out_size, void* d_ws, size_t ws_size,
                              hipStream_t stream) {
    const float* x   = (const float*)d_in[0];   // [B,S,D] fp32
    const float* Wx  = (const float*)d_in[1];   // [T,D,D] fp32
    const float* bx  = (const float*)d_in[2];   // [T,D]   fp32
    const float* p   = (const float*)d_in[3];   // [T,1,D] fp32
    float* out = (float*)d_out;

    unsigned short* wsw = (unsigned short*)d_ws;            // 131072 bf16 = 256 KB
    float* simg = (float*)((char*)d_ws + 262144);           // 65536*8 fp32 = 2 MB

    prep_kernel<<<dim3(512), dim3(256), 0, stream>>>(Wx, wsw);
    sim_kernel<<<dim3(Mq / 256), dim3(256), 0, stream>>>(x, p, simg);
    main_kernel<<<dim3(Mq / 128), dim3(256), 0, stream>>>(x, wsw, bx, simg, out);
}

// Round 2
// 112.274 us; speedup vs baseline: 1.0972x; 1.0972x over previous
//
#include <hip/hip_runtime.h>

// Problem constants
#define Bq 32
#define Sq 2048
#define Dq 128
#define Tq 8
#define Mq (Bq * Sq)   // 65536 rows

typedef __attribute__((ext_vector_type(8))) short bf16x8;
typedef __attribute__((ext_vector_type(4))) float f32x4;

static __device__ __forceinline__ unsigned short f2bf(float f) {
    unsigned int u = __float_as_uint(f);
    unsigned int r = (u + 0x7FFFu + ((u >> 16) & 1u)) >> 16;
    return (unsigned short)r;
}

// ---------------------------------------------------------------------------
// Kernel 1: W [T,D,D] fp32 -> bf16, swizzled into MFMA B-fragment order.
// B operand of mfma_f32_16x16x32_bf16: lane holds B[k = quad*8 + j][n = lane&15]
// = W[e = n][d = k].  Flat index (((t*8 + nt)*4 + k)*64 + lane)*8 + j  ->
// hot-loop loads are lane-contiguous 16B = perfectly coalesced.
// ---------------------------------------------------------------------------
__global__ void prep_kernel(const float* __restrict__ W, unsigned short* __restrict__ wsw) {
    int i = blockIdx.x * 256 + threadIdx.x;   // grid covers exactly T*D*D = 131072
    int j    = i & 7;
    int lane = (i >> 3) & 63;
    int k    = (i >> 9) & 3;
    int n    = (i >> 11) & 7;
    int t    = i >> 14;
    int e = n * 16 + (lane & 15);
    int d = k * 32 + (lane >> 4) * 8 + j;
    wsw[i] = f2bf(W[(t * 128 + e) * 128 + d]);
}

// ---------------------------------------------------------------------------
// Kernel 2 (fused): per 128-row tile:
//   phase A: stage x -> bf16 LDS (2 threads/row, fp32 kept in registers),
//            compute fp32 p-dots + |x|^2 inline, pair shuffle-reduce,
//            softmax -> simT LDS.   (replaces the old standalone sim kernel)
//   phase B: MFMA GEMM vs pre-swizzled W with explicit 2-deep B-fragment
//            double buffer (compile-time n so accumulators stay in VGPRs).
//   epilogue: out = x + sum_t sim*(y+bias), residual re-read from global (L2-hot).
// ---------------------------------------------------------------------------
__global__ __launch_bounds__(256, 2) void main_kernel(const float* __restrict__ x,
                                                      const unsigned short* __restrict__ wsw,
                                                      const float* __restrict__ bx,
                                                      const float* __restrict__ p,
                                                      float* __restrict__ out) {
    __shared__ unsigned short xs[128][136];  // +16B pad: row stride 272B (16B-aligned)
    __shared__ float simT[Tq][128];
    __shared__ float bxl[Tq][128];
    __shared__ float4 p4[Tq][32];
    __shared__ float pinv[Tq];

    int tid = threadIdx.x;
    size_t m0 = (size_t)blockIdx.x * 128;

    int r = tid >> 1;      // local row 0..127
    int h = tid & 1;       // half-row 0/1

    // issue x loads early (overlap with p/bias staging + barriers)
    const float4* xg = reinterpret_cast<const float4*>(x + (m0 + r) * 128) + h * 16;
    float4 xv[16];
    #pragma unroll
    for (int j = 0; j < 16; j++) xv[j] = xg[j];

    // stage p (8x128 fp32) and bias (8x128 fp32)
    reinterpret_cast<float4*>(&p4[0][0])[tid] = reinterpret_cast<const float4*>(p)[tid];
    reinterpret_cast<float4*>(&bxl[0][0])[tid] = reinterpret_cast<const float4*>(bx)[tid];
    __syncthreads();
    if (tid < Tq) {
        float s = 0.f;
        #pragma unroll
        for (int i = 0; i < 32; i++) {
            float4 v = p4[tid][i];
            s += v.x * v.x + v.y * v.y + v.z * v.z + v.w * v.w;
        }
        pinv[tid] = rsqrtf(s);
    }
    __syncthreads();

    // --- fp32 dots + |x|^2 over this thread's half-row, bf16 convert+store ---
    float dot[Tq];
    #pragma unroll
    for (int t = 0; t < Tq; t++) dot[t] = 0.f;
    float ssq = 0.f;
    #pragma unroll
    for (int j = 0; j < 16; j++) {
        float4 v = xv[j];
        ssq += v.x * v.x + v.y * v.y + v.z * v.z + v.w * v.w;
        #pragma unroll
        for (int t = 0; t < Tq; t++) {
            float4 pv = p4[t][h * 16 + j];
            dot[t] += v.x * pv.x + v.y * pv.y + v.z * pv.z + v.w * pv.w;
        }
    }
    #pragma unroll
    for (int jj = 0; jj < 8; jj++) {
        float4 v0 = xv[2 * jj], v1 = xv[2 * jj + 1];
        bf16x8 b;
        b[0] = (short)f2bf(v0.x); b[1] = (short)f2bf(v0.y);
        b[2] = (short)f2bf(v0.z); b[3] = (short)f2bf(v0.w);
        b[4] = (short)f2bf(v1.x); b[5] = (short)f2bf(v1.y);
        b[6] = (short)f2bf(v1.z); b[7] = (short)f2bf(v1.w);
        *reinterpret_cast<bf16x8*>(&xs[r][h * 64 + jj * 8]) = b;
    }
    // pair-reduce (lanes 2r, 2r+1 adjacent)
    ssq += __shfl_xor(ssq, 1);
    #pragma unroll
    for (int t = 0; t < Tq; t++) dot[t] += __shfl_xor(dot[t], 1);
    float xinv = rsqrtf(ssq);
    float c[Tq], mx = -1e30f;
    #pragma unroll
    for (int t = 0; t < Tq; t++) {
        c[t] = dot[t] * xinv * pinv[t];
        mx = fmaxf(mx, c[t]);
    }
    float sum = 0.f;
    #pragma unroll
    for (int t = 0; t < Tq; t++) { c[t] = __expf(c[t] - mx); sum += c[t]; }
    float inv = 1.f / sum;
    #pragma unroll
    for (int i = 0; i < 4; i++) simT[h * 4 + i][r] = c[h * 4 + i] * inv;
    __syncthreads();

    // --- GEMM phase ---
    int wid  = tid >> 6;
    int lane = tid & 63;
    int l16  = lane & 15;
    int quad = lane >> 4;
    int mrow = (wid >> 1) * 64;
    int ncol = (wid & 1) * 64;
    int nt0  = ncol >> 4;

    // A fragments: lane holds A[m=lane&15][k=quad*8+j]; reused across all 8 t.
    bf16x8 a[4][4];
    #pragma unroll
    for (int mt = 0; mt < 4; mt++)
        #pragma unroll
        for (int k = 0; k < 4; k++)
            a[mt][k] = *reinterpret_cast<const bf16x8*>(&xs[mrow + mt * 16 + l16][k * 32 + quad * 8]);

    f32x4 o[4][4] = {};

    const bf16x8* wbase = reinterpret_cast<const bf16x8*>(wsw);
    bf16x8 bf[2][4];
    #pragma unroll
    for (int k = 0; k < 4; k++)
        bf[0][k] = wbase[((size_t)(0 * 8 + nt0) * 4 + k) * 64 + lane];

    #pragma unroll 1
    for (int t = 0; t < Tq; t++) {
        f32x4 s[4];
        #pragma unroll
        for (int mt = 0; mt < 4; mt++)
            s[mt] = *reinterpret_cast<const f32x4*>(&simT[t][mrow + mt * 16 + quad * 4]);

        #pragma unroll
        for (int n = 0; n < 4; n++) {       // compile-time n: o[][] stays in VGPRs
            const int cur = n & 1;
            // prefetch fragments for (t, n+1) (wraps to (t+1,0); t=7,n=3 wraps to t=0, unused)
            {
                const int n2 = (n + 1) & 3;
                int t2 = (n == 3) ? ((t + 1) & 7) : t;
                #pragma unroll
                for (int k = 0; k < 4; k++)
                    bf[cur ^ 1][k] = wbase[((size_t)(t2 * 8 + nt0 + n2) * 4 + k) * 64 + lane];
            }
            f32x4 y[4] = {};
            #pragma unroll
            for (int k = 0; k < 4; k++)
                #pragma unroll
                for (int mt = 0; mt < 4; mt++)
                    y[mt] = __builtin_amdgcn_mfma_f32_16x16x32_bf16(a[mt][k], bf[cur][k], y[mt], 0, 0, 0);
            float bias = bxl[t][ncol + n * 16 + l16];
            #pragma unroll
            for (int mt = 0; mt < 4; mt++)
                #pragma unroll
                for (int rr = 0; rr < 4; rr++)
                    o[mt][n][rr] += s[mt][rr] * (y[mt][rr] + bias);
        }
    }

    // --- epilogue: fp32 residual + store. C/D layout: col=lane&15, row=quad*4+reg ---
    #pragma unroll
    for (int mt = 0; mt < 4; mt++)
        #pragma unroll
        for (int rr = 0; rr < 4; rr++) {
            size_t row = m0 + mrow + mt * 16 + quad * 4 + rr;
            #pragma unroll
            for (int n = 0; n < 4; n++) {
                size_t idx = row * 128 + ncol + n * 16 + l16;
                out[idx] = x[idx] + o[mt][n][rr];
            }
        }
}

extern "C" void kernel_launch(void* const* d_in, const int* in_sizes, int n_in,
                              void* d_out, int out_size, void* d_ws, size_t ws_size,
                              hipStream_t stream) {
    const float* x   = (const float*)d_in[0];   // [B,S,D] fp32
    const float* Wx  = (const float*)d_in[1];   // [T,D,D] fp32
    const float* bx  = (const float*)d_in[2];   // [T,D]   fp32
    const float* p   = (const float*)d_in[3];   // [T,1,D] fp32
    float* out = (float*)d_out;

    unsigned short* wsw = (unsigned short*)d_ws;   // 131072 bf16 = 256 KB

    prep_kernel<<<dim3(512), dim3(256), 0, stream>>>(Wx, wsw);
    main_kernel<<<dim3(Mq / 128), dim3(256), 0, stream>>>(x, wsw, bx, p, out);
}